// Round 1
// baseline (7197.082 us; speedup 1.0000x reference)
//
#include <hip/hip_runtime.h>
#include <stdint.h>

// Problem dims (fixed)
#define T_ 256
#define B_ 128
#define I_ 512
#define H_ 1024

typedef __attribute__((ext_vector_type(8))) short short8;
typedef __attribute__((ext_vector_type(4))) float f32x4;

__device__ __forceinline__ unsigned short f2bf(float f) {
  unsigned u = __float_as_uint(f);
  u += 0x7FFFu + ((u >> 16) & 1u);   // RNE
  return (unsigned short)(u >> 16);
}
__device__ __forceinline__ float bf2f(unsigned short s) {
  return __uint_as_float(((unsigned)s) << 16);
}
__device__ __forceinline__ float ftanh(float x) {
  float e = __expf(2.0f * x);
  return 1.0f - 2.0f / (e + 1.0f);
}

// ---------------- fp32 -> bf16 convert (vectorized, 8 elem/thread) -------------
__global__ __launch_bounds__(256) void cvt_kernel(const float* __restrict__ in,
                                                  unsigned short* __restrict__ out,
                                                  int n8) {
  int i = blockIdx.x * 256 + threadIdx.x;
  if (i >= n8) return;
  const float4* p = (const float4*)in + (size_t)i * 2;
  float4 a = p[0], b = p[1];
  uint4 o;
  o.x = (unsigned)f2bf(a.x) | ((unsigned)f2bf(a.y) << 16);
  o.y = (unsigned)f2bf(a.z) | ((unsigned)f2bf(a.w) << 16);
  o.z = (unsigned)f2bf(b.x) | ((unsigned)f2bf(b.y) << 16);
  o.w = (unsigned)f2bf(b.z) | ((unsigned)f2bf(b.w) << 16);
  ((uint4*)out)[i] = o;
}

// ---------------- xp GEMM: xp[m][n] = sum_k x[m][k]*W_ih[n][k] + b_ih[n]+b_hh[n]
// 128x128 tile, BK=64, 4 waves (2x2), global_load_lds staging w/ XOR swizzle.
__global__ __launch_bounds__(256) void gemm_xp(const unsigned short* __restrict__ A,
                                               const unsigned short* __restrict__ Bw,
                                               const float* __restrict__ b_ih,
                                               const float* __restrict__ b_hh,
                                               unsigned short* __restrict__ xp) {
  __shared__ unsigned short Al[8192];  // 128 rows x 8 granules x 8 bf16 (16 KB)
  __shared__ unsigned short Bl[8192];
  int tid = threadIdx.x, lane = tid & 63, w = tid >> 6;
  int wm = w & 1, wn = w >> 1;
  int bx = blockIdx.x;
  int m0 = (bx >> 3) * 128, n0 = (bx & 7) * 128;

  f32x4 acc[4][4];
#pragma unroll
  for (int i = 0; i < 4; ++i)
#pragma unroll
    for (int j = 0; j < 4; ++j) acc[i][j] = (f32x4){0.f, 0.f, 0.f, 0.f};

  for (int kb = 0; kb < 512; kb += 64) {
#pragma unroll
    for (int i = 0; i < 4; ++i) {
      int S = (w * 4 + i) * 64 + lane;     // slot 0..1023
      int row = S >> 3, pg = S & 7;
      int gk = ((pg ^ (row & 7)) << 3);    // logical k offset (elements)
      const unsigned short* ga = A + (size_t)(m0 + row) * 512 + kb + gk;
      const unsigned short* gb = Bw + (size_t)(n0 + row) * 512 + kb + gk;
      __builtin_amdgcn_global_load_lds(
          (const __attribute__((address_space(1))) unsigned int*)ga,
          (__attribute__((address_space(3))) unsigned int*)&Al[(size_t)((w * 4 + i) * 64) * 8],
          16, 0, 0);
      __builtin_amdgcn_global_load_lds(
          (const __attribute__((address_space(1))) unsigned int*)gb,
          (__attribute__((address_space(3))) unsigned int*)&Bl[(size_t)((w * 4 + i) * 64) * 8],
          16, 0, 0);
    }
    asm volatile("s_waitcnt vmcnt(0)" ::: "memory");
    __syncthreads();

#pragma unroll
    for (int c = 0; c < 2; ++c) {
      short8 av[4], bv[4];
      int gg = c * 4 + (lane >> 4);
#pragma unroll
      for (int mt = 0; mt < 4; ++mt) {
        int rowa = wm * 64 + mt * 16 + (lane & 15);
        av[mt] = *(const short8*)&Al[(rowa * 8 + (gg ^ (rowa & 7))) * 8];
        int rowb = wn * 64 + mt * 16 + (lane & 15);
        bv[mt] = *(const short8*)&Bl[(rowb * 8 + (gg ^ (rowb & 7))) * 8];
      }
#pragma unroll
      for (int mt = 0; mt < 4; ++mt)
#pragma unroll
        for (int nt = 0; nt < 4; ++nt)
          acc[mt][nt] = __builtin_amdgcn_mfma_f32_16x16x32_bf16(av[mt], bv[nt], acc[mt][nt], 0, 0, 0);
    }
    __syncthreads();
  }

  int cl = lane & 15, qd = lane >> 4;
#pragma unroll
  for (int nt = 0; nt < 4; ++nt) {
    int col = n0 + wn * 64 + nt * 16 + cl;
    float bias = b_ih[col] + b_hh[col];
#pragma unroll
    for (int mt = 0; mt < 4; ++mt) {
#pragma unroll
      for (int r = 0; r < 4; ++r) {
        int m = m0 + wm * 64 + mt * 16 + qd * 4 + r;
        xp[(size_t)m * 1024 + col] = f2bf(acc[mt][nt][r] + bias);
      }
    }
  }
}

// ---------------- the scan -------------------------------------------------
// 512 one-wave WGs: group g = blk&7 (16 batches), H-slice hj = blk>>3 (16 rows).
// W_hh slice pinned in LDS (bf16 B-frag layout) for all 256 steps.
// h fragments loaded straight from global hs[t-1] into MFMA A-operand regs.
// Per-group monotone arrival counter; relaxed spin + agent fences.
__global__ __launch_bounds__(64) void scan_kernel(const float* __restrict__ Whh,
                                                  const unsigned short* __restrict__ xp,
                                                  unsigned short* __restrict__ hs,
                                                  unsigned* __restrict__ flags) {
  __shared__ unsigned short wfr[16384];  // [c:32][lane:64][8 bf16] = 32 KB
  int tid = threadIdx.x;                 // 0..63
  int g = blockIdx.x & 7;                // batch group (XCD-local under %8 heuristic)
  int hj = blockIdx.x >> 3;              // 0..63 H-slice
  int r = tid & 15, q = tid >> 4;
  int b0 = g * 16;

  // ---- load W_hh slice into LDS B-frag layout: frag lane l holds
  // W[hj*16 + (l&15)][c*32 + (l>>4)*8 + j], fp32->bf16.
  {
    const float* wsrc = Whh + (size_t)(hj * 16 + r) * 1024 + q * 8;
#pragma unroll 4
    for (int c = 0; c < 32; ++c) {
      float4 v0 = *(const float4*)(wsrc + c * 32);
      float4 v1 = *(const float4*)(wsrc + c * 32 + 4);
      short8 s;
      s[0] = (short)f2bf(v0.x); s[1] = (short)f2bf(v0.y);
      s[2] = (short)f2bf(v0.z); s[3] = (short)f2bf(v0.w);
      s[4] = (short)f2bf(v1.x); s[5] = (short)f2bf(v1.y);
      s[6] = (short)f2bf(v1.z); s[7] = (short)f2bf(v1.w);
      *(short8*)&wfr[(size_t)(c * 64 + tid) * 8] = s;
    }
  }
  __syncthreads();

  size_t colg = (size_t)hj * 16 + r;
  unsigned* flag = &flags[g * 16];  // 64-B stride between groups

  // ---- step 0: h0 = tanh(xp[0]) (h_{-1} = 0)
#pragma unroll
  for (int rr = 0; rr < 4; ++rr) {
    int m = q * 4 + rr;
    size_t idx = (size_t)(b0 + m) * 1024 + colg;
    hs[idx] = f2bf(ftanh(bf2f(xp[idx])));
  }
  __threadfence();
  if (tid == 0) atomicAdd(flag, 1u);

  int guard = 0;
  for (int t = 1; t < 256; ++t) {
    unsigned target = 64u * (unsigned)t;
    while (__hip_atomic_load(flag, __ATOMIC_RELAXED, __HIP_MEMORY_SCOPE_AGENT) < target) {
      if (++guard > (1 << 23)) break;  // safety valve: wrong-but-terminating
    }
    __threadfence();  // acquire: make other XCDs' hs[t-1] stores visible

    // h fragments: lane holds h[b0 + (tid&15)][c*32 + q*8 .. +7] (16 B each)
    const unsigned short* hsrc = hs + ((size_t)(t - 1) * 128 + b0 + r) * 1024 + q * 8;
    uint4 hv[32];
#pragma unroll
    for (int c = 0; c < 32; ++c) hv[c] = *(const uint4*)(hsrc + c * 32);

    f32x4 acc = (f32x4){0.f, 0.f, 0.f, 0.f};
#pragma unroll
    for (int c = 0; c < 32; ++c) {
      short8 a = __builtin_bit_cast(short8, hv[c]);
      short8 bvv = *(const short8*)&wfr[(size_t)(c * 64 + tid) * 8];
      acc = __builtin_amdgcn_mfma_f32_16x16x32_bf16(a, bvv, acc, 0, 0, 0);
    }

#pragma unroll
    for (int rr = 0; rr < 4; ++rr) {
      int m = q * 4 + rr;
      size_t idx = ((size_t)t * 128 + b0 + m) * 1024 + colg;
      float h = ftanh(acc[rr] + bf2f(xp[idx]));
      hs[idx] = f2bf(h);
    }
    __threadfence();  // release: hs stores before arrival
    if (tid == 0) atomicAdd(flag, 1u);
  }
}

// ---------------- head GEMV: out[t*128+b] = dot(hs[t,b,:], W_fc) + b_fc ------
__global__ __launch_bounds__(256) void head_gemv(const unsigned short* __restrict__ hs,
                                                 const float* __restrict__ Wfc,
                                                 const float* __restrict__ bfc,
                                                 float* __restrict__ out) {
  int gtid = blockIdx.x * 256 + threadIdx.x;
  int wv = gtid >> 6, l = gtid & 63;
  const unsigned short* row = hs + (size_t)wv * 1024 + l * 16;
  uint4 p0 = *(const uint4*)row;
  uint4 p1 = *(const uint4*)(row + 8);
  const float4* wf = (const float4*)(Wfc + l * 16);
  float4 w0 = wf[0], w1 = wf[1], w2 = wf[2], w3 = wf[3];
  float acc = 0.f;
#define DOT2(u, wa, wb) \
  acc += __uint_as_float((u) << 16) * (wa) + __uint_as_float((u) & 0xffff0000u) * (wb);
  DOT2(p0.x, w0.x, w0.y) DOT2(p0.y, w0.z, w0.w)
  DOT2(p0.z, w1.x, w1.y) DOT2(p0.w, w1.z, w1.w)
  DOT2(p1.x, w2.x, w2.y) DOT2(p1.y, w2.z, w2.w)
  DOT2(p1.z, w3.x, w3.y) DOT2(p1.w, w3.z, w3.w)
#undef DOT2
#pragma unroll
  for (int off = 32; off; off >>= 1) acc += __shfl_down(acc, off, 64);
  if (l == 0) out[wv] = acc + bfc[0];
}

// ---------------- launcher --------------------------------------------------
extern "C" void kernel_launch(void* const* d_in, const int* in_sizes, int n_in,
                              void* d_out, int out_size, void* d_ws, size_t ws_size,
                              hipStream_t stream) {
  (void)in_sizes; (void)n_in; (void)out_size; (void)ws_size;
  const float* x   = (const float*)d_in[0];
  const float* Wih = (const float*)d_in[1];
  const float* Whh = (const float*)d_in[2];
  const float* bih = (const float*)d_in[3];
  const float* bhh = (const float*)d_in[4];
  const float* Wfc = (const float*)d_in[5];
  const float* bfc = (const float*)d_in[6];
  float* out = (float*)d_out;

  char* ws = (char*)d_ws;
  // Workspace layout (bytes). xb/wb alias the hs region: they are dead once
  // gemm_xp completes, before scan_kernel writes hs. Total: 128 MB + 512 B.
  const size_t XP_OFF = 0;                     // 32768*1024*2 = 64 MB (bf16)
  const size_t HS_OFF = 67108864;              // 256*128*1024*2 = 64 MB (bf16)
  const size_t XB_OFF = HS_OFF;                // 32 MB (bf16 x), dead after gemm
  const size_t WB_OFF = HS_OFF + 33554432;     // 1 MB  (bf16 W_ih), dead after gemm
  const size_t FL_OFF = 134217728;             // 512 B flags
  unsigned short* xp = (unsigned short*)(ws + XP_OFF);
  unsigned short* hs = (unsigned short*)(ws + HS_OFF);
  unsigned short* xb = (unsigned short*)(ws + XB_OFF);
  unsigned short* wb = (unsigned short*)(ws + WB_OFF);
  unsigned* flags = (unsigned*)(ws + FL_OFF);

  hipMemsetAsync(flags, 0, 512, stream);                        // ws is 0xAA-poisoned
  cvt_kernel<<<8192, 256, 0, stream>>>(x, xb, 2097152);         // x fp32 -> bf16
  cvt_kernel<<<256, 256, 0, stream>>>(Wih, wb, 65536);          // W_ih fp32 -> bf16
  gemm_xp<<<2048, 256, 0, stream>>>(xb, wb, bih, bhh, xp);      // xp = x@W_ih^T + biases
  scan_kernel<<<512, 64, 0, stream>>>(Whh, xp, hs, flags);      // 256-step recurrence
  head_gemv<<<8192, 256, 0, stream>>>(hs, Wfc, bfc, out);       // out = hs@W_fc^T + b_fc
}

// Round 2
// 2093.090 us; speedup vs baseline: 3.4385x; 3.4385x over previous
//
#include <hip/hip_runtime.h>
#include <stdint.h>

// Problem dims (fixed)
#define T_ 256
#define B_ 128
#define I_ 512
#define H_ 1024

typedef __attribute__((ext_vector_type(8))) short short8;
typedef __attribute__((ext_vector_type(4))) float f32x4;
typedef __attribute__((ext_vector_type(4))) unsigned int u32x4;

__device__ __forceinline__ unsigned short f2bf(float f) {
  unsigned u = __float_as_uint(f);
  u += 0x7FFFu + ((u >> 16) & 1u);   // RNE
  return (unsigned short)(u >> 16);
}
__device__ __forceinline__ float bf2f(unsigned short s) {
  return __uint_as_float(((unsigned)s) << 16);
}
__device__ __forceinline__ float ftanh(float x) {
  float e = __expf(2.0f * x);
  return 1.0f - 2.0f / (e + 1.0f);
}

// ---------------- fp32 -> bf16 convert (vectorized, 8 elem/thread) -------------
__global__ __launch_bounds__(256) void cvt_kernel(const float* __restrict__ in,
                                                  unsigned short* __restrict__ out,
                                                  int n8) {
  int i = blockIdx.x * 256 + threadIdx.x;
  if (i >= n8) return;
  const float4* p = (const float4*)in + (size_t)i * 2;
  float4 a = p[0], b = p[1];
  uint4 o;
  o.x = (unsigned)f2bf(a.x) | ((unsigned)f2bf(a.y) << 16);
  o.y = (unsigned)f2bf(a.z) | ((unsigned)f2bf(a.w) << 16);
  o.z = (unsigned)f2bf(b.x) | ((unsigned)f2bf(b.y) << 16);
  o.w = (unsigned)f2bf(b.z) | ((unsigned)f2bf(b.w) << 16);
  ((uint4*)out)[i] = o;
}

// ---------------- xp GEMM: xp[m][n] = sum_k x[m][k]*W_ih[n][k] + b_ih[n]+b_hh[n]
__global__ __launch_bounds__(256) void gemm_xp(const unsigned short* __restrict__ A,
                                               const unsigned short* __restrict__ Bw,
                                               const float* __restrict__ b_ih,
                                               const float* __restrict__ b_hh,
                                               unsigned short* __restrict__ xp) {
  __shared__ unsigned short Al[8192];  // 128 rows x 8 granules x 8 bf16 (16 KB)
  __shared__ unsigned short Bl[8192];
  int tid = threadIdx.x, lane = tid & 63, w = tid >> 6;
  int wm = w & 1, wn = w >> 1;
  int bx = blockIdx.x;
  int m0 = (bx >> 3) * 128, n0 = (bx & 7) * 128;

  f32x4 acc[4][4];
#pragma unroll
  for (int i = 0; i < 4; ++i)
#pragma unroll
    for (int j = 0; j < 4; ++j) acc[i][j] = (f32x4){0.f, 0.f, 0.f, 0.f};

  for (int kb = 0; kb < 512; kb += 64) {
#pragma unroll
    for (int i = 0; i < 4; ++i) {
      int S = (w * 4 + i) * 64 + lane;     // slot 0..1023
      int row = S >> 3, pg = S & 7;
      int gk = ((pg ^ (row & 7)) << 3);    // logical k offset (elements)
      const unsigned short* ga = A + (size_t)(m0 + row) * 512 + kb + gk;
      const unsigned short* gb = Bw + (size_t)(n0 + row) * 512 + kb + gk;
      __builtin_amdgcn_global_load_lds(
          (const __attribute__((address_space(1))) unsigned int*)ga,
          (__attribute__((address_space(3))) unsigned int*)&Al[(size_t)((w * 4 + i) * 64) * 8],
          16, 0, 0);
      __builtin_amdgcn_global_load_lds(
          (const __attribute__((address_space(1))) unsigned int*)gb,
          (__attribute__((address_space(3))) unsigned int*)&Bl[(size_t)((w * 4 + i) * 64) * 8],
          16, 0, 0);
    }
    asm volatile("s_waitcnt vmcnt(0)" ::: "memory");
    __syncthreads();

#pragma unroll
    for (int c = 0; c < 2; ++c) {
      short8 av[4], bv[4];
      int gg = c * 4 + (lane >> 4);
#pragma unroll
      for (int mt = 0; mt < 4; ++mt) {
        int rowa = wm * 64 + mt * 16 + (lane & 15);
        av[mt] = *(const short8*)&Al[(rowa * 8 + (gg ^ (rowa & 7))) * 8];
        int rowb = wn * 64 + mt * 16 + (lane & 15);
        bv[mt] = *(const short8*)&Bl[(rowb * 8 + (gg ^ (rowb & 7))) * 8];
      }
#pragma unroll
      for (int mt = 0; mt < 4; ++mt)
#pragma unroll
        for (int nt = 0; nt < 4; ++nt)
          acc[mt][nt] = __builtin_amdgcn_mfma_f32_16x16x32_bf16(av[mt], bv[nt], acc[mt][nt], 0, 0, 0);
    }
    __syncthreads();
  }

  int cl = lane & 15, qd = lane >> 4;
#pragma unroll
  for (int nt = 0; nt < 4; ++nt) {
    int col = n0 + wn * 64 + nt * 16 + cl;
    float bias = b_ih[col] + b_hh[col];
#pragma unroll
    for (int mt = 0; mt < 4; ++mt) {
#pragma unroll
      for (int r = 0; r < 4; ++r) {
        int m = m0 + wm * 64 + mt * 16 + qd * 4 + r;
        xp[(size_t)m * 1024 + col] = f2bf(acc[mt][nt][r] + bias);
      }
    }
  }
}

// ---------------- the scan -------------------------------------------------
// 512 one-wave WGs: group g = blk&7 (16 batches), H-slice hj = blk>>3 (16 rows).
// W_hh slice pinned in LDS for all 256 steps. NO fences, NO atomics in the
// step loop: producers publish h[t] with sc0+sc1 write-through stores (MALL
// is the coherence point), then one vmcnt(0), then a per-slice epoch word.
// Consumers poll the 64 epoch words (one lane each) with sc0+sc1 loads, then
// read h[t-1] with PLAIN cached loads (lines cannot be stale: kernel-entry
// acquire invalidates L1/L2, and no one touches hs[t] addresses pre-publish;
// post-publish values are immutable, so same-XCD consumers share L2 fills).
__global__ __launch_bounds__(64) void scan_kernel(const float* __restrict__ Whh,
                                                  const unsigned short* __restrict__ xp,
                                                  unsigned short* __restrict__ hs,
                                                  unsigned* __restrict__ epochs) {
  __shared__ unsigned short wfr[16384];        // [c:32][lane:64][8 bf16] = 32 KB
  __shared__ __align__(16) unsigned short tile[16 * 24];  // padded 16x16 out tile
  const int tid = threadIdx.x;                 // 0..63
  const int g = blockIdx.x & 7;                // batch group
  const int hj = blockIdx.x >> 3;              // 0..63 H-slice
  const int r = tid & 15, q = tid >> 4;
  const int b0 = g * 16;

  // ---- load W_hh slice into LDS B-frag layout: frag lane l holds
  // W[hj*16 + (l&15)][c*32 + (l>>4)*8 + j], fp32->bf16.
  {
    const float* wsrc = Whh + (size_t)(hj * 16 + r) * 1024 + q * 8;
#pragma unroll 4
    for (int c = 0; c < 32; ++c) {
      float4 v0 = *(const float4*)(wsrc + c * 32);
      float4 v1 = *(const float4*)(wsrc + c * 32 + 4);
      short8 s;
      s[0] = (short)f2bf(v0.x); s[1] = (short)f2bf(v0.y);
      s[2] = (short)f2bf(v0.z); s[3] = (short)f2bf(v0.w);
      s[4] = (short)f2bf(v1.x); s[5] = (short)f2bf(v1.y);
      s[6] = (short)f2bf(v1.z); s[7] = (short)f2bf(v1.w);
      *(short8*)&wfr[(size_t)(c * 64 + tid) * 8] = s;
    }
  }
  __syncthreads();

  const size_t colg = (size_t)hj * 16 + r;
  const unsigned* epg = epochs + g * 64;   // this group's 64 epoch words
  unsigned* myep = epochs + g * 64 + hj;   // my slot

  int guard = 0;

  for (int s = 0; s < 256; ++s) {
    float hval[4];

    if (s == 0) {
      // h0 = tanh(xp[0]) (h_{-1} = 0)
#pragma unroll
      for (int rr = 0; rr < 4; ++rr) {
        size_t idx = (size_t)(b0 + q * 4 + rr) * 1024 + colg;
        hval[rr] = ftanh(bf2f(xp[idx]));
      }
    } else {
      // ---- wait for all 64 slices of h[s-1]: lane l polls epoch slot l.
      // Epoch value after publishing h[s'] is s'+1, so we need e >= s.
      // Poison 0xAAAAAAAA is negative under signed compare -> never passes.
      {
        const unsigned* ea = epg + tid;  // 64 lanes -> 64 slots
        while (true) {
          int e;
          asm volatile("global_load_dword %0, %1, off sc0 sc1\n\ts_waitcnt vmcnt(0)"
                       : "=v"(e)
                       : "v"((unsigned long long)(uintptr_t)ea)
                       : "memory");
          if (__all(e >= s)) break;
          if (++guard > (1 << 22)) break;  // fail-safe: terminate, fail check
        }
      }

      // ---- h[s-1] fragments (plain cached loads; A-frag layout:
      // lane (r,q) holds h[b0+r][c*32 + q*8 .. +7], 16 B each)
      const unsigned short* hsrc = hs + ((size_t)(s - 1) * 128 + b0 + r) * 1024 + q * 8;
      u32x4 hv[32];
#pragma unroll
      for (int c = 0; c < 32; ++c) hv[c] = *(const u32x4*)(hsrc + c * 32);

      // ---- two independent MFMA chains (halve dependent latency)
      f32x4 acc0 = (f32x4){0.f, 0.f, 0.f, 0.f};
      f32x4 acc1 = (f32x4){0.f, 0.f, 0.f, 0.f};
#pragma unroll
      for (int c = 0; c < 16; ++c) {
        short8 a0 = __builtin_bit_cast(short8, hv[2 * c]);
        short8 a1 = __builtin_bit_cast(short8, hv[2 * c + 1]);
        short8 b0v = *(const short8*)&wfr[(size_t)((2 * c) * 64 + tid) * 8];
        short8 b1v = *(const short8*)&wfr[(size_t)((2 * c + 1) * 64 + tid) * 8];
        acc0 = __builtin_amdgcn_mfma_f32_16x16x32_bf16(a0, b0v, acc0, 0, 0, 0);
        acc1 = __builtin_amdgcn_mfma_f32_16x16x32_bf16(a1, b1v, acc1, 0, 0, 0);
      }

#pragma unroll
      for (int rr = 0; rr < 4; ++rr) {
        size_t idx = ((size_t)s * 128 + b0 + q * 4 + rr) * 1024 + colg;
        hval[rr] = ftanh(acc0[rr] + acc1[rr] + bf2f(xp[idx]));
      }
    }

    // ---- publish h[s]: pack via LDS so stores are 16-B dwordx4.
    __syncthreads();  // prior step's tile reads are done
#pragma unroll
    for (int rr = 0; rr < 4; ++rr) tile[(q * 4 + rr) * 24 + r] = f2bf(hval[rr]);
    __syncthreads();
    if (tid < 32) {
      int row = tid & 15, half = tid >> 4;
      u32x4 v = *(const u32x4*)&tile[row * 24 + half * 8];
      unsigned long long addr = (unsigned long long)(uintptr_t)(
          hs + ((size_t)s * 128 + b0 + row) * 1024 + (size_t)hj * 16 + half * 8);
      asm volatile("global_store_dwordx4 %0, %1, off sc0 sc1"
                   :: "v"(addr), "v"(v) : "memory");
    }
    asm volatile("s_waitcnt vmcnt(0)" ::: "memory");  // data at MALL before epoch
    if (tid == 0) {
      unsigned val = (unsigned)(s + 1);
      asm volatile("global_store_dword %0, %1, off sc0 sc1"
                   :: "v"((unsigned long long)(uintptr_t)myep), "v"(val) : "memory");
    }
  }
}

// ---------------- head GEMV: out[t*128+b] = dot(hs[t,b,:], W_fc) + b_fc ------
__global__ __launch_bounds__(256) void head_gemv(const unsigned short* __restrict__ hs,
                                                 const float* __restrict__ Wfc,
                                                 const float* __restrict__ bfc,
                                                 float* __restrict__ out) {
  int gtid = blockIdx.x * 256 + threadIdx.x;
  int wv = gtid >> 6, l = gtid & 63;
  const unsigned short* row = hs + (size_t)wv * 1024 + l * 16;
  uint4 p0 = *(const uint4*)row;
  uint4 p1 = *(const uint4*)(row + 8);
  const float4* wf = (const float4*)(Wfc + l * 16);
  float4 w0 = wf[0], w1 = wf[1], w2 = wf[2], w3 = wf[3];
  float acc = 0.f;
#define DOT2(u, wa, wb) \
  acc += __uint_as_float((u) << 16) * (wa) + __uint_as_float((u) & 0xffff0000u) * (wb);
  DOT2(p0.x, w0.x, w0.y) DOT2(p0.y, w0.z, w0.w)
  DOT2(p0.z, w1.x, w1.y) DOT2(p0.w, w1.z, w1.w)
  DOT2(p1.x, w2.x, w2.y) DOT2(p1.y, w2.z, w2.w)
  DOT2(p1.z, w3.x, w3.y) DOT2(p1.w, w3.z, w3.w)
#undef DOT2
#pragma unroll
  for (int off = 32; off; off >>= 1) acc += __shfl_down(acc, off, 64);
  if (l == 0) out[wv] = acc + bfc[0];
}

// ---------------- launcher --------------------------------------------------
extern "C" void kernel_launch(void* const* d_in, const int* in_sizes, int n_in,
                              void* d_out, int out_size, void* d_ws, size_t ws_size,
                              hipStream_t stream) {
  (void)in_sizes; (void)n_in; (void)out_size; (void)ws_size;
  const float* x   = (const float*)d_in[0];
  const float* Wih = (const float*)d_in[1];
  const float* Whh = (const float*)d_in[2];
  const float* bih = (const float*)d_in[3];
  const float* bhh = (const float*)d_in[4];
  const float* Wfc = (const float*)d_in[5];
  const float* bfc = (const float*)d_in[6];
  float* out = (float*)d_out;

  char* ws = (char*)d_ws;
  // Workspace layout (bytes). xb/wb alias the hs region: dead before scan.
  const size_t XP_OFF = 0;                     // 64 MB (bf16 xp)
  const size_t HS_OFF = 67108864;              // 64 MB (bf16 hs)
  const size_t XB_OFF = HS_OFF;                // 32 MB (bf16 x), dead after gemm
  const size_t WB_OFF = HS_OFF + 33554432;     // 1 MB  (bf16 W_ih), dead after gemm
  const size_t FL_OFF = 134217728;             // 2 KB epochs (poison-safe: signed poll)
  unsigned short* xp = (unsigned short*)(ws + XP_OFF);
  unsigned short* hs = (unsigned short*)(ws + HS_OFF);
  unsigned short* xb = (unsigned short*)(ws + XB_OFF);
  unsigned short* wb = (unsigned short*)(ws + WB_OFF);
  unsigned* epochs = (unsigned*)(ws + FL_OFF);

  cvt_kernel<<<8192, 256, 0, stream>>>(x, xb, 2097152);         // x fp32 -> bf16
  cvt_kernel<<<256, 256, 0, stream>>>(Wih, wb, 65536);          // W_ih fp32 -> bf16
  gemm_xp<<<2048, 256, 0, stream>>>(xb, wb, bih, bhh, xp);      // xp = x@W_ih^T + b
  scan_kernel<<<512, 64, 0, stream>>>(Whh, xp, hs, epochs);     // 256-step recurrence
  head_gemv<<<8192, 256, 0, stream>>>(hs, Wfc, bfc, out);       // out = hs@W_fc^T + b
}